// Round 13
// baseline (265.742 us; speedup 1.0000x reference)
//
#include <hip/hip_runtime.h>

// NCC loss: 1 - mean( cross^2 / (pvar*tvar + 1e-8) ) over 9^3 zero-padded
// box windows, input (4,1,160,160,160) fp32.
//
// R18: R17 refuted byte-limiting (FETCH -9% but dur +23%: makespan =
// max(block critical path, work/slots); ZCHUNK=40 restored). R18 attacks the
// largest per-step resource + serial tail: the reduction wave's 60 scalar
// LDS reads (plus 90 conflict-cy and 45 addr-calc VALU). s2 is TRANSPOSED to
// [f][x][y] with y-stride 28 (16B aligned):
//   - red reads 12 y-taps as 3 x ds_read_b128 per field (15 wave-reads vs
//     60), all via one base reg + immediate offsets;
//   - staging writes remain 15 scalar b32 (strided 28), <=2-way banks (free),
//     one base reg + immediate offsets;
//   - LDS 19.2 -> 17.9 KB.
// Everything else = R16 verbatim (best, 122.8us): 3 cols/thread all-lanes
// staging, 64 VGPR, 3 stg + 1 red wave, ZCHUNK 40, depth-1 prefetch, one
// barrier/step, double-buffered s2.
// Tripwires: WRITE_SIZE ~50KB (spill); SQ_LDS_BANK_CONFLICT should DROP <1.5M.

#define DSZ    160
#define NBATCH 4
#define RAD    4
#define TX     16
#define TY     16
#define ZCHUNK 40
#define SLICE  (DSZ*DSZ)
#define VOL    (DSZ*DSZ*DSZ)
#define WINV   (1.0f/729.0f)
#define NVOX_INV (1.0f/16384000.0f)

#define NROW 24        // halo rows per tile
#define BLK  256       // 3 staging waves (tid<192, all active) + 1 reduction wave

#define S2_YS 28                 // y stride per x-column (24 rows + pad, 16B-aligned)
#define S2_FS (16*S2_YS)         // 448 floats per field ([x][y])
#define S2_BUF (5*S2_FS)         // 2240 floats per parity buffer

__device__ __forceinline__ float dpp_shl1(float x) {  // lane i <- lane i+1 (16-lane row, OOB=0)
    return __int_as_float(__builtin_amdgcn_update_dpp(0, __float_as_int(x), 0x101, 0xf, 0xf, true));
}
__device__ __forceinline__ float dpp_shl2(float x) {  // lane i <- lane i+2
    return __int_as_float(__builtin_amdgcn_update_dpp(0, __float_as_int(x), 0x102, 0xf, 0xf, true));
}
__device__ __forceinline__ float dpp_shl3(float x) {  // lane i <- lane i+3
    return __int_as_float(__builtin_amdgcn_update_dpp(0, __float_as_int(x), 0x103, 0xf, 0xf, true));
}

__global__ __launch_bounds__(BLK, 4)
void ncc_main(const float* __restrict__ pred, const float* __restrict__ tgt,
              float* __restrict__ accum)
{
    const int tid = threadIdx.x;
    const int row = tid >> 3;      // 0..23 halo row (staging threads)
    const int g   = tid & 7;       // 0..7 col-triple group; ALL active
    const int ox  = blockIdx.x * TX;
    const int oy  = blockIdx.y * TY;
    const int batch = blockIdx.z >> 2;
    const int z0  = (blockIdx.z & 3) * ZCHUNK;

    __shared__ float s2[2*S2_BUF];   // 17.9 KB, double-buffered [f][x][y pad28]

    const bool stg = (tid < 192);
    const bool red = (tid >= 192);               // dedicated reduction wave
    const int  gy  = oy - RAD + row;
    const int  gx0 = ox - RAD + g*3;             // 3 halo cols per thread
    const bool ldok = stg && (gy >= 0) && (gy < DSZ) && (gx0 >= 0) && (gx0 + 2 < DSZ);
    const int  base = batch*VOL + gy*DSZ + gx0;  // only used under ldok

    // register ring of raw slice values (own 3 columns), chunk-local slots
    float rp[9][3], rt[9][3];
    float zs[5][3];
    #pragma unroll
    for (int k = 0; k < 9; ++k)
        #pragma unroll
        for (int j = 0; j < 3; ++j) { rp[k][j] = 0.f; rt[k][j] = 0.f; }
    #pragma unroll
    for (int f = 0; f < 5; ++f)
        #pragma unroll
        for (int j = 0; j < 3; ++j) zs[f][j] = 0.f;

    // ---- warm-up: chunk-local slices 0..7 (z = z0-4 .. z0+3) -> slots 0..7
    if (stg) {
        #pragma unroll
        for (int i = 0; i < 8; ++i) {
            int z = z0 - RAD + i;
            if (z >= 0) {                       // uniform; z < DSZ always here
                float3 p3 = {0,0,0}, t3 = {0,0,0};
                if (ldok) {
                    p3 = *(const float3*)(pred + base + z*SLICE);
                    t3 = *(const float3*)(tgt  + base + z*SLICE);
                }
                const float pc[3] = {p3.x, p3.y, p3.z};
                const float tc[3] = {t3.x, t3.y, t3.z};
                #pragma unroll
                for (int j = 0; j < 3; ++j) {
                    zs[0][j] += pc[j];        zs[1][j] += tc[j];
                    zs[2][j] += pc[j]*pc[j];  zs[3][j] += tc[j]*tc[j];
                    zs[4][j] += pc[j]*tc[j];
                    rp[i][j] = pc[j];  rt[i][j] = tc[j];
                }
            }
        }
    }

    // ---- streaming prefetch of the next add-slice (depth 1) ----
    int za = z0 + RAD;                      // absolute z of next fetch
    int zmax = z0 + ZCHUNK + RAD;           // last useful slice + 1
    if (zmax > DSZ) zmax = DSZ;
    float3 pa3 = {0,0,0}, ta3 = {0,0,0};

#define PF_NEXT() do {                                                        \
    float3 _p = {0,0,0}, _t = {0,0,0};                                        \
    if (ldok && za < zmax) {                                                  \
        _p = *(const float3*)(pred + base + za*SLICE);                        \
        _t = *(const float3*)(tgt  + base + za*SLICE);                        \
    }                                                                         \
    pa3 = _p; ta3 = _t; ++za;                                                 \
} while (0)

    if (stg) PF_NEXT();  // slice for step 0

    int pb = 1;          // parity buffer toggle (first step -> 0)
    float acc = 0.f;

#define NCC_STEP(SLOT) do {                                                   \
    pb ^= 1;                                                                  \
    float* s2w = s2 + pb*S2_BUF;                                              \
    if (stg) {                                                                \
        const float pc[3] = {pa3.x, pa3.y, pa3.z};                            \
        const float tc[3] = {ta3.x, ta3.y, ta3.z};                            \
        PF_NEXT();  /* issue slice s+1; full step to complete */              \
        _Pragma("unroll")                                                     \
        for (int j = 0; j < 3; ++j) {                                         \
            float ps = rp[SLOT][j], qs = rt[SLOT][j];                         \
            float d0 = pc[j] - ps, d1 = tc[j] - qs;                           \
            zs[0][j] += d0;                                                   \
            zs[1][j] += d1;                                                   \
            zs[2][j] += d0*(pc[j] + ps);                                      \
            zs[3][j] += d1*(tc[j] + qs);                                      \
            zs[4][j] += pc[j]*tc[j] - ps*qs;                                  \
            rp[SLOT][j] = pc[j];  rt[SLOT][j] = tc[j];                        \
        }                                                                     \
        /* one address register, all 15 writes at immediate offsets */        \
        float* wbase = &s2w[3*g*S2_YS + row];                                 \
        _Pragma("unroll")                                                     \
        for (int f = 0; f < 5; ++f) {                                         \
            float v0  = zs[f][0];                                             \
            float v01 = v0 + zs[f][1];                                        \
            float G   = v01 + zs[f][2];        /* 3-col group sum */          \
            float G1 = dpp_shl1(G);                                           \
            float G2 = dpp_shl2(G);                                           \
            float A0 = dpp_shl3(v0);           /* v0(m+3)  */                 \
            float A1 = dpp_shl3(v01);          /* v01(m+3) */                 \
            float S  = G + G1 + G2;            /* halo cols 3m..3m+8 */       \
            if (g < 5) {                                                      \
                wbase[f*S2_FS + 0*S2_YS] = S;            /* out x=3m   */     \
                wbase[f*S2_FS + 1*S2_YS] = S - v0  + A0; /* out x=3m+1 */     \
                wbase[f*S2_FS + 2*S2_YS] = S - v01 + A1; /* out x=3m+2 */     \
            } else if (g == 5) {                                              \
                wbase[f*S2_FS + 0*S2_YS] = S;            /* out x=15   */     \
            }                                                                 \
        }                                                                     \
    }                                                                         \
    __syncthreads();                                                          \
    if (red) {                                                                \
        const int x = tid & 15, yq = ((tid >> 4) & 3)*4;                      \
        const float* rbase = &s2w[x*S2_YS + yq];                              \
        float S[5][4];                                                        \
        _Pragma("unroll")                                                     \
        for (int f = 0; f < 5; ++f) {                                         \
            /* 12 consecutive y-taps: 3 x ds_read_b128 at immediate offs */   \
            float4 a = *(const float4*)(rbase + f*S2_FS + 0);                 \
            float4 b = *(const float4*)(rbase + f*S2_FS + 4);                 \
            float4 c = *(const float4*)(rbase + f*S2_FS + 8);                 \
            float run = a.x+a.y+a.z+a.w + b.x+b.y+b.z+b.w + c.x;              \
            S[f][0] = run;                                                    \
            run += c.y - a.x;  S[f][1] = run;                                 \
            run += c.z - a.y;  S[f][2] = run;                                 \
            run += c.w - a.z;  S[f][3] = run;                                 \
        }                                                                     \
        _Pragma("unroll")                                                     \
        for (int i = 0; i < 4; ++i) {                                         \
            float Sp = S[0][i], St = S[1][i];                                 \
            float cross = S[4][i] - Sp*St*WINV;                               \
            float pv    = S[2][i] - Sp*Sp*WINV;                               \
            float tv    = S[3][i] - St*St*WINV;                               \
            acc += cross*cross / (pv*tv + 1e-8f);                             \
        }                                                                     \
    }                                                                         \
} while (0)

    // steps s=0..3: slots (s+8)%9 = 8,0,1,2
    NCC_STEP(8); NCC_STEP(0); NCC_STEP(1); NCC_STEP(2);
    // steps s=4..39: slot sequence (s+8)%9 is 9-periodic: 3,4,5,6,7,8,0,1,2
    for (int it = 0; it < 4; ++it) {
        NCC_STEP(3); NCC_STEP(4); NCC_STEP(5);
        NCC_STEP(6); NCC_STEP(7); NCC_STEP(8);
        NCC_STEP(0); NCC_STEP(1); NCC_STEP(2);
    }
#undef NCC_STEP
#undef PF_NEXT

    // all cc partials live in the reduction wave (tid 192..255)
    if (red) {
        float v = acc;
        #pragma unroll
        for (int off = 32; off > 0; off >>= 1) v += __shfl_down(v, off, 64);
        if (tid == 192) atomicAdd(accum, v);
    }
}

__global__ void ncc_final(const float* __restrict__ accum, float* __restrict__ out)
{
    out[0] = 1.0f - accum[0] * NVOX_INV;
}

extern "C" void kernel_launch(void* const* d_in, const int* in_sizes, int n_in,
                              void* d_out, int out_size, void* d_ws, size_t ws_size,
                              hipStream_t stream)
{
    const float* pred = (const float*)d_in[0];
    const float* tgt  = (const float*)d_in[1];
    float* out = (float*)d_out;
    float* ws  = (float*)d_ws;

    hipMemsetAsync(ws, 0, sizeof(float), stream);
    dim3 grid(DSZ/TX, DSZ/TY, NBATCH*4);   // 10 x 10 x 16 = 1600 blocks
    ncc_main<<<grid, BLK, 0, stream>>>(pred, tgt, ws);
    ncc_final<<<1, 1, 0, stream>>>(ws, out);
}

// Round 14
// 242.561 us; speedup vs baseline: 1.0956x; 1.0956x over previous
//
#include <hip/hip_runtime.h>

// NCC loss: 1 - mean( cross^2 / (pvar*tvar + 1e-8) ) over 9^3 zero-padded
// box windows, input (4,1,160,160,160) fp32.
//
// R19: R18 regressed (transposed-s2 b128 reads still conflicted, +FETCH):
// reverted to R16 (122.8us best). R19 = "R10 done right": halve the barrier
// count (40->20) by processing a SLICE PAIR per barrier, while KEEPING the
// depth-1 prefetch-ahead R10 lost. Per double-step: consume prefetched pair
// (slices 2u,2u+1) -> issue next pair (8 loads, a full ~1500cy double-step
// to complete) -> R16's PROC on slice A into bufA, PROC on slice B into bufB
// -> ONE barrier -> red wave reduces bufA+bufB. LDS 4 buffers = 38.4 KB ->
// still exactly 4 blocks/CU. Staging body, 3-col DPP prefix, red body all
// R16-verbatim. Register delta: +6 persistent floats (second pair); budget
// 128 at launch_bounds(256,4) -> tripwire below arbitrates.
// Tripwires: WRITE_SIZE ~50KB (spill => reject, R16 is plateau);
// LDS_Block_Size 38400; conflicts ~5.8M (unchanged per slice).

#define DSZ    160
#define NBATCH 4
#define RAD    4
#define TX     16
#define TY     16
#define ZCHUNK 40
#define SLICE  (DSZ*DSZ)
#define VOL    (DSZ*DSZ*DSZ)
#define WINV   (1.0f/729.0f)
#define NVOX_INV (1.0f/16384000.0f)

#define NROW 24        // halo rows per tile
#define BLK  256       // 3 staging waves (tid<192, all active) + 1 reduction wave

#define S2_RS 20                 // row stride: 16 outputs + pad
#define S2_FS (NROW*S2_RS)       // 480 floats per field
#define S2_BUF (5*S2_FS)         // 2400 floats per staging buffer

__device__ __forceinline__ float dpp_shl1(float x) {  // lane i <- lane i+1 (16-lane row, OOB=0)
    return __int_as_float(__builtin_amdgcn_update_dpp(0, __float_as_int(x), 0x101, 0xf, 0xf, true));
}
__device__ __forceinline__ float dpp_shl2(float x) {  // lane i <- lane i+2
    return __int_as_float(__builtin_amdgcn_update_dpp(0, __float_as_int(x), 0x102, 0xf, 0xf, true));
}
__device__ __forceinline__ float dpp_shl3(float x) {  // lane i <- lane i+3
    return __int_as_float(__builtin_amdgcn_update_dpp(0, __float_as_int(x), 0x103, 0xf, 0xf, true));
}

__global__ __launch_bounds__(BLK, 4)
void ncc_main(const float* __restrict__ pred, const float* __restrict__ tgt,
              float* __restrict__ accum)
{
    const int tid = threadIdx.x;
    const int row = tid >> 3;      // 0..23 halo row (staging threads)
    const int g   = tid & 7;       // 0..7 col-triple group; ALL active
    const int ox  = blockIdx.x * TX;
    const int oy  = blockIdx.y * TY;
    const int batch = blockIdx.z >> 2;
    const int z0  = (blockIdx.z & 3) * ZCHUNK;

    __shared__ float s2[4*S2_BUF];   // 38.4 KB: 2 double-buffered pairs (A,B)

    const bool stg = (tid < 192);
    const bool red = (tid >= 192);               // dedicated reduction wave
    const int  gy  = oy - RAD + row;
    const int  gx0 = ox - RAD + g*3;             // 3 halo cols per thread
    const bool ldok = stg && (gy >= 0) && (gy < DSZ) && (gx0 >= 0) && (gx0 + 2 < DSZ);
    const int  base = batch*VOL + gy*DSZ + gx0;  // only used under ldok

    // register ring of raw slice values (own 3 columns), chunk-local slots
    float rp[9][3], rt[9][3];
    float zs[5][3];
    #pragma unroll
    for (int k = 0; k < 9; ++k)
        #pragma unroll
        for (int j = 0; j < 3; ++j) { rp[k][j] = 0.f; rt[k][j] = 0.f; }
    #pragma unroll
    for (int f = 0; f < 5; ++f)
        #pragma unroll
        for (int j = 0; j < 3; ++j) zs[f][j] = 0.f;

    // ---- warm-up: chunk-local slices 0..7 (z = z0-4 .. z0+3) -> slots 0..7
    if (stg) {
        #pragma unroll
        for (int i = 0; i < 8; ++i) {
            int z = z0 - RAD + i;
            if (z >= 0) {                       // uniform; z < DSZ always here
                float3 p3 = {0,0,0}, t3 = {0,0,0};
                if (ldok) {
                    p3 = *(const float3*)(pred + base + z*SLICE);
                    t3 = *(const float3*)(tgt  + base + z*SLICE);
                }
                const float pc[3] = {p3.x, p3.y, p3.z};
                const float tc[3] = {t3.x, t3.y, t3.z};
                #pragma unroll
                for (int j = 0; j < 3; ++j) {
                    zs[0][j] += pc[j];        zs[1][j] += tc[j];
                    zs[2][j] += pc[j]*pc[j];  zs[3][j] += tc[j]*tc[j];
                    zs[4][j] += pc[j]*tc[j];
                    rp[i][j] = pc[j];  rt[i][j] = tc[j];
                }
            }
        }
    }

    // ---- streaming prefetch of the next slice PAIR (depth 1 pair) ----
    int za = z0 + RAD;                      // absolute z of next pair's first slice
    int zmax = z0 + ZCHUNK + RAD;           // last useful slice + 1
    if (zmax > DSZ) zmax = DSZ;
    float3 paA = {0,0,0}, taA = {0,0,0};    // pair slice 0
    float3 paB = {0,0,0}, taB = {0,0,0};    // pair slice 1

#define PF_PAIR() do {                                                        \
    float3 _pA = {0,0,0}, _tA = {0,0,0}, _pB = {0,0,0}, _tB = {0,0,0};        \
    if (ldok) {                                                               \
        if (za < zmax) {                                                      \
            _pA = *(const float3*)(pred + base + za*SLICE);                   \
            _tA = *(const float3*)(tgt  + base + za*SLICE);                   \
        }                                                                     \
        if (za+1 < zmax) {                                                    \
            _pB = *(const float3*)(pred + base + (za+1)*SLICE);               \
            _tB = *(const float3*)(tgt  + base + (za+1)*SLICE);               \
        }                                                                     \
    }                                                                         \
    paA = _pA; taA = _tA; paB = _pB; taB = _tB; za += 2;                      \
} while (0)

    if (stg) PF_PAIR();  // pair for double-step 0

    int pb = 1;          // pair-parity toggle (first double-step -> 0)
    float acc = 0.f;

// R16's verified per-slice staging body (ring/zs update + 3-col DPP prefix)
#define PROC(SLOT, P3, T3, DSTBUF) do {                                       \
    const float pc[3] = {P3.x, P3.y, P3.z};                                   \
    const float tc[3] = {T3.x, T3.y, T3.z};                                   \
    _Pragma("unroll")                                                         \
    for (int j = 0; j < 3; ++j) {                                             \
        float ps = rp[SLOT][j], qs = rt[SLOT][j];                             \
        float d0 = pc[j] - ps, d1 = tc[j] - qs;                               \
        zs[0][j] += d0;                                                       \
        zs[1][j] += d1;                                                       \
        zs[2][j] += d0*(pc[j] + ps);                                          \
        zs[3][j] += d1*(tc[j] + qs);                                          \
        zs[4][j] += pc[j]*tc[j] - ps*qs;                                      \
        rp[SLOT][j] = pc[j];  rt[SLOT][j] = tc[j];                            \
    }                                                                         \
    _Pragma("unroll")                                                         \
    for (int f = 0; f < 5; ++f) {                                             \
        float v0  = zs[f][0];                                                 \
        float v01 = v0 + zs[f][1];                                            \
        float G   = v01 + zs[f][2];        /* 3-col group sum */              \
        float G1 = dpp_shl1(G);                                               \
        float G2 = dpp_shl2(G);                                               \
        float A0 = dpp_shl3(v0);           /* v0(m+3)  */                     \
        float A1 = dpp_shl3(v01);          /* v01(m+3) */                     \
        float S  = G + G1 + G2;            /* halo cols 3m..3m+8 */           \
        float* dst = &(DSTBUF)[f*S2_FS + row*S2_RS + 3*g];                    \
        if (g < 5) {                                                          \
            dst[0] = S;                    /* out 3m   */                     \
            dst[1] = S - v0  + A0;         /* out 3m+1 */                     \
            dst[2] = S - v01 + A1;         /* out 3m+2 */                     \
        } else if (g == 5) {                                                  \
            dst[0] = S;                    /* out 15   */                     \
        }                                                                     \
    }                                                                         \
} while (0)

// R16's verified reduction body over one staged buffer
#define REDUCE(SRC) do {                                                      \
    const int x = tid & 15, yq = ((tid >> 4) & 3)*4;                          \
    float S[5][4];                                                            \
    _Pragma("unroll")                                                         \
    for (int f = 0; f < 5; ++f) {                                             \
        const float* col = &(SRC)[f*S2_FS + x];                               \
        float r0 = col[(yq+0)*S2_RS], r1 = col[(yq+1)*S2_RS];                 \
        float r2 = col[(yq+2)*S2_RS], r3 = col[(yq+3)*S2_RS];                 \
        float run = r0+r1+r2+r3 + col[(yq+4)*S2_RS] + col[(yq+5)*S2_RS]       \
                  + col[(yq+6)*S2_RS] + col[(yq+7)*S2_RS];                    \
        run += col[(yq+8)*S2_RS];        S[f][0] = run;                       \
        run += col[(yq+9)*S2_RS]  - r0;  S[f][1] = run;                       \
        run += col[(yq+10)*S2_RS] - r1;  S[f][2] = run;                       \
        run += col[(yq+11)*S2_RS] - r2;  S[f][3] = run;                       \
    }                                                                         \
    _Pragma("unroll")                                                         \
    for (int i = 0; i < 4; ++i) {                                             \
        float Sp = S[0][i], St = S[1][i];                                     \
        float cross = S[4][i] - Sp*St*WINV;                                   \
        float pv    = S[2][i] - Sp*Sp*WINV;                                   \
        float tv    = S[3][i] - St*St*WINV;                                   \
        acc += cross*cross / (pv*tv + 1e-8f);                                 \
    }                                                                         \
} while (0)

// one double-step: 2 slices, 1 barrier; prefetch pair issued at top
#define NCC2(SA, SB) do {                                                     \
    pb ^= 1;                                                                  \
    float* bufA = s2 + pb*2*S2_BUF;                                           \
    float* bufB = bufA + S2_BUF;                                              \
    if (stg) {                                                                \
        float3 cpA = paA, ctA = taA, cpB = paB, ctB = taB;                    \
        PF_PAIR();  /* issue next pair; full double-step to complete */       \
        PROC(SA, cpA, ctA, bufA);                                             \
        PROC(SB, cpB, ctB, bufB);                                             \
    }                                                                         \
    __syncthreads();                                                          \
    if (red) { REDUCE(bufA); REDUCE(bufB); }                                  \
} while (0)

    // double-step u consumes steps 2u,2u+1 -> slots (2u+8)%9,(2u+9)%9;
    // period 9 in u. 20 = 2 + 2*9, all indices compile-time static.
    NCC2(8,0); NCC2(1,2);
    for (int it = 0; it < 2; ++it) {
        NCC2(3,4); NCC2(5,6); NCC2(7,8);
        NCC2(0,1); NCC2(2,3); NCC2(4,5);
        NCC2(6,7); NCC2(8,0); NCC2(1,2);
    }
#undef NCC2
#undef REDUCE
#undef PROC
#undef PF_PAIR

    // all cc partials live in the reduction wave (tid 192..255)
    if (red) {
        float v = acc;
        #pragma unroll
        for (int off = 32; off > 0; off >>= 1) v += __shfl_down(v, off, 64);
        if (tid == 192) atomicAdd(accum, v);
    }
}

__global__ void ncc_final(const float* __restrict__ accum, float* __restrict__ out)
{
    out[0] = 1.0f - accum[0] * NVOX_INV;
}

extern "C" void kernel_launch(void* const* d_in, const int* in_sizes, int n_in,
                              void* d_out, int out_size, void* d_ws, size_t ws_size,
                              hipStream_t stream)
{
    const float* pred = (const float*)d_in[0];
    const float* tgt  = (const float*)d_in[1];
    float* out = (float*)d_out;
    float* ws  = (float*)d_ws;

    hipMemsetAsync(ws, 0, sizeof(float), stream);
    dim3 grid(DSZ/TX, DSZ/TY, NBATCH*4);   // 10 x 10 x 16 = 1600 blocks
    ncc_main<<<grid, BLK, 0, stream>>>(pred, tgt, ws);
    ncc_final<<<1, 1, 0, stream>>>(ws, out);
}

// Round 15
// 214.136 us; speedup vs baseline: 1.2410x; 1.1327x over previous
//
#include <hip/hip_runtime.h>

// NCC loss: 1 - mean( cross^2 / (pvar*tvar + 1e-8) ) over 9^3 zero-padded
// box windows, input (4,1,160,160,160) fp32.
//
// R20: R19 (pair-per-barrier) regressed 50% -> reverted to R16 (122.8us,
// best). Cross-kernel invariant: R9 (512 slots x 2400cy/step) == R16 (716 x
// 3300) -> fixed per-CU step throughput; residual stall ~2000cy/step is the
// barrier vmcnt-drain waiting on halo loads served by REMOTE XCD L2 / HBM
// (consecutive hw blocks = consecutive x-tiles round-robined over 8 XCDs, so
// xy-neighbors sharing 2.25x halo never share an L2).
// R20 = R16 + bijective XCD swizzle (T1; 1600%8==0): lid=(bid&7)*200+(bid>>3)
// -> XCD k gets logical tiles [k*200, k*200+200) = two complete 10x10
// xy-planes; halo re-reads become local-L2 hits (~2MB working set << 4MB).
// Everything else R16-verbatim: 3 cols/thread all-lane staging, 54-float
// ring, DPP shl1-3 x-prefix, 3 stg + 1 red wave, ZCHUNK 40, depth-1
// prefetch, one barrier/step, double-buffered s2, launch_bounds(256,4).
// Expected: FETCH 331 -> ~230-290 MB; dur -> 105-115us if latency-limited,
// unchanged if issue-limited (then this is the structural ceiling).

#define DSZ    160
#define NBATCH 4
#define RAD    4
#define TX     16
#define TY     16
#define ZCHUNK 40
#define SLICE  (DSZ*DSZ)
#define VOL    (DSZ*DSZ*DSZ)
#define WINV   (1.0f/729.0f)
#define NVOX_INV (1.0f/16384000.0f)

#define NROW 24        // halo rows per tile
#define BLK  256       // 3 staging waves (tid<192, all active) + 1 reduction wave

#define S2_RS 20                 // row stride: 16 outputs + pad
#define S2_FS (NROW*S2_RS)       // 480 floats per field
#define S2_BUF (5*S2_FS)         // 2400 floats per parity buffer

__device__ __forceinline__ float dpp_shl1(float x) {  // lane i <- lane i+1 (16-lane row, OOB=0)
    return __int_as_float(__builtin_amdgcn_update_dpp(0, __float_as_int(x), 0x101, 0xf, 0xf, true));
}
__device__ __forceinline__ float dpp_shl2(float x) {  // lane i <- lane i+2
    return __int_as_float(__builtin_amdgcn_update_dpp(0, __float_as_int(x), 0x102, 0xf, 0xf, true));
}
__device__ __forceinline__ float dpp_shl3(float x) {  // lane i <- lane i+3
    return __int_as_float(__builtin_amdgcn_update_dpp(0, __float_as_int(x), 0x103, 0xf, 0xf, true));
}

__global__ __launch_bounds__(BLK, 4)
void ncc_main(const float* __restrict__ pred, const float* __restrict__ tgt,
              float* __restrict__ accum)
{
    const int tid = threadIdx.x;
    const int row = tid >> 3;      // 0..23 halo row (staging threads)
    const int g   = tid & 7;       // 0..7 col-triple group; ALL active

    // ---- XCD-aware bijective swizzle (T1): hw bid -> logical tile ----
    // hw dispatch id (x fastest). XCD = bid % 8 (round-robin). Give XCD k a
    // contiguous span of 200 logical tiles = two full 10x10 xy planes.
    const int bid = blockIdx.x + 10*(blockIdx.y + 10*blockIdx.z);
    const int lid = (bid & 7)*200 + (bid >> 3);       // bijective: 1600%8==0
    const int lz  = lid / 100;                        // 0..15: (batch,chunk)
    const int lxy = lid - lz*100;
    const int ly  = lxy / 10;
    const int lx  = lxy - ly*10;

    const int ox  = lx * TX;
    const int oy  = ly * TY;
    const int batch = lz >> 2;
    const int z0  = (lz & 3) * ZCHUNK;

    __shared__ float s2[2*S2_BUF];   // 19.2 KB, double-buffered [f][y][x pad20]

    const bool stg = (tid < 192);
    const bool red = (tid >= 192);               // dedicated reduction wave
    const int  gy  = oy - RAD + row;
    const int  gx0 = ox - RAD + g*3;             // 3 halo cols per thread
    const bool ldok = stg && (gy >= 0) && (gy < DSZ) && (gx0 >= 0) && (gx0 + 2 < DSZ);
    const int  base = batch*VOL + gy*DSZ + gx0;  // only used under ldok

    // register ring of raw slice values (own 3 columns), chunk-local slots
    float rp[9][3], rt[9][3];
    float zs[5][3];
    #pragma unroll
    for (int k = 0; k < 9; ++k)
        #pragma unroll
        for (int j = 0; j < 3; ++j) { rp[k][j] = 0.f; rt[k][j] = 0.f; }
    #pragma unroll
    for (int f = 0; f < 5; ++f)
        #pragma unroll
        for (int j = 0; j < 3; ++j) zs[f][j] = 0.f;

    // ---- warm-up: chunk-local slices 0..7 (z = z0-4 .. z0+3) -> slots 0..7
    if (stg) {
        #pragma unroll
        for (int i = 0; i < 8; ++i) {
            int z = z0 - RAD + i;
            if (z >= 0) {                       // uniform; z < DSZ always here
                float3 p3 = {0,0,0}, t3 = {0,0,0};
                if (ldok) {
                    p3 = *(const float3*)(pred + base + z*SLICE);
                    t3 = *(const float3*)(tgt  + base + z*SLICE);
                }
                const float pc[3] = {p3.x, p3.y, p3.z};
                const float tc[3] = {t3.x, t3.y, t3.z};
                #pragma unroll
                for (int j = 0; j < 3; ++j) {
                    zs[0][j] += pc[j];        zs[1][j] += tc[j];
                    zs[2][j] += pc[j]*pc[j];  zs[3][j] += tc[j]*tc[j];
                    zs[4][j] += pc[j]*tc[j];
                    rp[i][j] = pc[j];  rt[i][j] = tc[j];
                }
            }
        }
    }

    // ---- streaming prefetch of the next add-slice (depth 1) ----
    int za = z0 + RAD;                      // absolute z of next fetch
    int zmax = z0 + ZCHUNK + RAD;           // last useful slice + 1
    if (zmax > DSZ) zmax = DSZ;
    float3 pa3 = {0,0,0}, ta3 = {0,0,0};

#define PF_NEXT() do {                                                        \
    float3 _p = {0,0,0}, _t = {0,0,0};                                        \
    if (ldok && za < zmax) {                                                  \
        _p = *(const float3*)(pred + base + za*SLICE);                        \
        _t = *(const float3*)(tgt  + base + za*SLICE);                        \
    }                                                                         \
    pa3 = _p; ta3 = _t; ++za;                                                 \
} while (0)

    if (stg) PF_NEXT();  // slice for step 0

    int pb = 1;          // parity buffer toggle (first step -> 0)
    float acc = 0.f;

#define NCC_STEP(SLOT) do {                                                   \
    pb ^= 1;                                                                  \
    float* s2w = s2 + pb*S2_BUF;                                              \
    if (stg) {                                                                \
        const float pc[3] = {pa3.x, pa3.y, pa3.z};                            \
        const float tc[3] = {ta3.x, ta3.y, ta3.z};                            \
        PF_NEXT();  /* issue slice s+1; full step to complete */              \
        _Pragma("unroll")                                                     \
        for (int j = 0; j < 3; ++j) {                                         \
            float ps = rp[SLOT][j], qs = rt[SLOT][j];                         \
            float d0 = pc[j] - ps, d1 = tc[j] - qs;                           \
            zs[0][j] += d0;                                                   \
            zs[1][j] += d1;                                                   \
            zs[2][j] += d0*(pc[j] + ps);                                      \
            zs[3][j] += d1*(tc[j] + qs);                                      \
            zs[4][j] += pc[j]*tc[j] - ps*qs;                                  \
            rp[SLOT][j] = pc[j];  rt[SLOT][j] = tc[j];                        \
        }                                                                     \
        _Pragma("unroll")                                                     \
        for (int f = 0; f < 5; ++f) {                                         \
            float v0  = zs[f][0];                                             \
            float v01 = v0 + zs[f][1];                                        \
            float G   = v01 + zs[f][2];        /* 3-col group sum */          \
            float G1 = dpp_shl1(G);                                           \
            float G2 = dpp_shl2(G);                                           \
            float A0 = dpp_shl3(v0);           /* v0(m+3)  */                 \
            float A1 = dpp_shl3(v01);          /* v01(m+3) */                 \
            float S  = G + G1 + G2;            /* halo cols 3m..3m+8 */       \
            float* dst = &s2w[f*S2_FS + row*S2_RS + 3*g];                     \
            if (g < 5) {                                                      \
                dst[0] = S;                    /* out 3m   */                 \
                dst[1] = S - v0  + A0;         /* out 3m+1 */                 \
                dst[2] = S - v01 + A1;         /* out 3m+2 */                 \
            } else if (g == 5) {                                              \
                dst[0] = S;                    /* out 15   */                 \
            }                                                                 \
        }                                                                     \
    }                                                                         \
    __syncthreads();                                                          \
    if (red) {                                                                \
        const int x = tid & 15, yq = ((tid >> 4) & 3)*4;                      \
        float S[5][4];                                                        \
        _Pragma("unroll")                                                     \
        for (int f = 0; f < 5; ++f) {                                         \
            const float* col = &s2w[f*S2_FS + x];                             \
            float r0 = col[(yq+0)*S2_RS], r1 = col[(yq+1)*S2_RS];             \
            float r2 = col[(yq+2)*S2_RS], r3 = col[(yq+3)*S2_RS];             \
            float run = r0+r1+r2+r3 + col[(yq+4)*S2_RS] + col[(yq+5)*S2_RS]   \
                      + col[(yq+6)*S2_RS] + col[(yq+7)*S2_RS];                \
            run += col[(yq+8)*S2_RS];        S[f][0] = run;                   \
            run += col[(yq+9)*S2_RS]  - r0;  S[f][1] = run;                   \
            run += col[(yq+10)*S2_RS] - r1;  S[f][2] = run;                   \
            run += col[(yq+11)*S2_RS] - r2;  S[f][3] = run;                   \
        }                                                                     \
        _Pragma("unroll")                                                     \
        for (int i = 0; i < 4; ++i) {                                         \
            float Sp = S[0][i], St = S[1][i];                                 \
            float cross = S[4][i] - Sp*St*WINV;                               \
            float pv    = S[2][i] - Sp*Sp*WINV;                               \
            float tv    = S[3][i] - St*St*WINV;                               \
            acc += cross*cross / (pv*tv + 1e-8f);                             \
        }                                                                     \
    }                                                                         \
} while (0)

    // steps s=0..3: slots (s+8)%9 = 8,0,1,2
    NCC_STEP(8); NCC_STEP(0); NCC_STEP(1); NCC_STEP(2);
    // steps s=4..39: slot sequence (s+8)%9 is 9-periodic: 3,4,5,6,7,8,0,1,2
    for (int it = 0; it < 4; ++it) {
        NCC_STEP(3); NCC_STEP(4); NCC_STEP(5);
        NCC_STEP(6); NCC_STEP(7); NCC_STEP(8);
        NCC_STEP(0); NCC_STEP(1); NCC_STEP(2);
    }
#undef NCC_STEP
#undef PF_NEXT

    // all cc partials live in the reduction wave (tid 192..255)
    if (red) {
        float v = acc;
        #pragma unroll
        for (int off = 32; off > 0; off >>= 1) v += __shfl_down(v, off, 64);
        if (tid == 192) atomicAdd(accum, v);
    }
}

__global__ void ncc_final(const float* __restrict__ accum, float* __restrict__ out)
{
    out[0] = 1.0f - accum[0] * NVOX_INV;
}

extern "C" void kernel_launch(void* const* d_in, const int* in_sizes, int n_in,
                              void* d_out, int out_size, void* d_ws, size_t ws_size,
                              hipStream_t stream)
{
    const float* pred = (const float*)d_in[0];
    const float* tgt  = (const float*)d_in[1];
    float* out = (float*)d_out;
    float* ws  = (float*)d_ws;

    hipMemsetAsync(ws, 0, sizeof(float), stream);
    dim3 grid(DSZ/TX, DSZ/TY, NBATCH*4);   // 10 x 10 x 16 = 1600 blocks
    ncc_main<<<grid, BLK, 0, stream>>>(pred, tgt, ws);
    ncc_final<<<1, 1, 0, stream>>>(ws, out);
}